// Round 3
// baseline (132.408 us; speedup 1.0000x reference)
//
#include <hip/hip_runtime.h>

// Problem constants
#define B_   8
#define TE_  256
#define TD_  256
#define D_   256
#define U_   256

// Workspace layout (float offsets).
#define AE_OFF    0        // (B*TE, U)  Ee = exp2(2*log2e * en@w_en)
#define AD_OFF    524288   // (B*TD, U)  Ed = exp2(2*log2e * de@w_de)
#define SUMEN_OFF 1048576  // (B, TD, D) sum_en
#define MAXMU_OFF 1572864  // (B, TD)    row max of mu'

__device__ __forceinline__ float fexp2(float x) {
#if __has_builtin(__builtin_amdgcn_exp2f)
  return __builtin_amdgcn_exp2f(x);
#else
  return exp2f(x);
#endif
}
__device__ __forceinline__ float frcp(float x) {
#if __has_builtin(__builtin_amdgcn_rcpf)
  return __builtin_amdgcn_rcpf(x);
#else
  return 1.0f / x;
#endif
}

#define LOG2E_F 1.4426950408889634f
#define TWO_LOG2E_F 2.8853900817779268f

// ---------------------------------------------------------------------------
// KA: Ee = exp2((en @ w_en) * 2log2e) ; Ed = exp2((de @ w_de) * 2log2e)
// tanh(ad+ae) = 1 - 2/(Ed*Ee+1). 64x64 tile, 4x4 microtile. grid (4,32,2).
// ---------------------------------------------------------------------------
__global__ __launch_bounds__(256) void coatt_ka_proj(
    const float* __restrict__ en, const float* __restrict__ de,
    const float* __restrict__ w_en, const float* __restrict__ w_de,
    float* __restrict__ ws) {
  const int which = blockIdx.z;
  const float* __restrict__ A = which ? de : en;     // (2048, 256)
  const float* __restrict__ W = which ? w_de : w_en; // (256, 256)
  float* __restrict__ out = ws + (which ? AD_OFF : AE_OFF);
  const int rowBase = blockIdx.y * 64;
  const int colBase = blockIdx.x * 64;
  __shared__ float As[16][68];  // A^T chunk: As[k][row]
  __shared__ float Bs[16][68];  // Bs[k][col]
  const int tid = threadIdx.x;
  const int tx = tid & 15, ty = tid >> 4;
  float acc[4][4] = {};
  for (int k0 = 0; k0 < D_; k0 += 16) {
    {
      const int r = tid >> 2;          // 0..63
      const int c = (tid & 3) * 4;     // 0,4,8,12
      const float4 a4 = *(const float4*)&A[(rowBase + r) * D_ + k0 + c];
      As[c + 0][r] = a4.x; As[c + 1][r] = a4.y;
      As[c + 2][r] = a4.z; As[c + 3][r] = a4.w;
      const int kk = tid >> 4;         // 0..15
      const int cc = (tid & 15) * 4;   // 0..60
      *(float4*)&Bs[kk][cc] = *(const float4*)&W[(k0 + kk) * U_ + colBase + cc];
    }
    __syncthreads();
#pragma unroll
    for (int k = 0; k < 16; ++k) {
      float av[4], bv[4];
      *(float4*)av = *(const float4*)&As[k][ty * 4];
      *(float4*)bv = *(const float4*)&Bs[k][tx * 4];
#pragma unroll
      for (int i = 0; i < 4; ++i)
#pragma unroll
        for (int j = 0; j < 4; ++j)
          acc[i][j] = fmaf(av[i], bv[j], acc[i][j]);
    }
    __syncthreads();
  }
#pragma unroll
  for (int i = 0; i < 4; ++i) {
    float4 o;
    o.x = fexp2(acc[i][0] * TWO_LOG2E_F);
    o.y = fexp2(acc[i][1] * TWO_LOG2E_F);
    o.z = fexp2(acc[i][2] * TWO_LOG2E_F);
    o.w = fexp2(acc[i][3] * TWO_LOG2E_F);
    *(float4*)&out[(rowBase + ty * 4 + i) * U_ + colBase + tx * 4] = o;
  }
}

// ---------------------------------------------------------------------------
// KB (fused): per block (b, 4 s-rows):
//   phase1: mu'[s][t] = sum_u (-2 nu_u) * rcp(fma(Ed[s,u], Ee[t,u], 1))
//           (thread t=tid owns a t-column; Ee chunk staged TRANSPOSED [u][t],
//            pad 260 -> 2-way bank aliasing = free; Ed/nu broadcast reads)
//   phase2: softmax over t per s-row in LDS (one wave per row, shuffles);
//           alphas stay in LDS; maxmu -> global
//   phase3: sum_en[s,:] = alphas[s,:] @ en[b,:,:], en chunks staged into the
//           dead EeT space, waves split t-range, LDS cross-wave reduce.
// mu/alphas NEVER touch global memory. grid (64, 8) = 512 blocks.
// ---------------------------------------------------------------------------
__global__ __launch_bounds__(256) void coatt_kb_fused(
    const float* __restrict__ nu, const float* __restrict__ en,
    float* __restrict__ ws) {
  const float* __restrict__ Ee = ws + AE_OFF;
  const float* __restrict__ Ed = ws + AD_OFF;
  float* __restrict__ sum_en = ws + SUMEN_OFF;
  float* __restrict__ maxmu = ws + MAXMU_OFF;
  const int b = blockIdx.y;
  const int sBase = blockIdx.x * 4;
  const int tid = threadIdx.x;
  const int w = tid >> 6, lane = tid & 63;

  __shared__ float EdS[4][256];   // 4 KB, broadcast-read only
  __shared__ float NUs[256];      // 1 KB, -2*nu
  __shared__ float EeT[16][260];  // 16.6 KB; reused as EN chunk / reduce buf
  __shared__ float Mu[4][260];    // 4.2 KB; mu' -> alphas

  // phase 0: stage EdS + NUs (coalesced)
  {
    const int r = tid >> 6, c4 = tid & 63;
    *(float4*)&EdS[r][c4 * 4] =
        *(const float4*)&Ed[(b * TD_ + sBase + r) * U_ + c4 * 4];
    NUs[tid] = -2.0f * nu[tid];
  }
  __syncthreads();

  // ---- phase 1: mu' ----
  float acc0 = 0.f, acc1 = 0.f, acc2 = 0.f, acc3 = 0.f;
  const int t = tid;
  for (int u0 = 0; u0 < U_; u0 += 16) {
    // stage EeT[u_local][t] transposed (16 rows x 256 t)
#pragma unroll
    for (int k = 0; k < 4; ++k) {
      const int f = tid + 256 * k;
      const int tt = f >> 2, c = f & 3;
      const float4 v = *(const float4*)&Ee[(b * TE_ + tt) * U_ + u0 + c * 4];
      EeT[c * 4 + 0][tt] = v.x;
      EeT[c * 4 + 1][tt] = v.y;
      EeT[c * 4 + 2][tt] = v.z;
      EeT[c * 4 + 3][tt] = v.w;
    }
    __syncthreads();
#pragma unroll
    for (int uq = 0; uq < 4; ++uq) {
      float nv[4];
      *(float4*)nv = *(const float4*)&NUs[u0 + uq * 4];  // broadcast
      float ee[4];
#pragma unroll
      for (int j = 0; j < 4; ++j) ee[j] = EeT[uq * 4 + j][t];  // stride-1
      float e0[4], e1[4], e2[4], e3[4];
      *(float4*)e0 = *(const float4*)&EdS[0][u0 + uq * 4];  // broadcast
      *(float4*)e1 = *(const float4*)&EdS[1][u0 + uq * 4];
      *(float4*)e2 = *(const float4*)&EdS[2][u0 + uq * 4];
      *(float4*)e3 = *(const float4*)&EdS[3][u0 + uq * 4];
#pragma unroll
      for (int j = 0; j < 4; ++j) {
        acc0 = fmaf(nv[j], frcp(fmaf(e0[j], ee[j], 1.0f)), acc0);
        acc1 = fmaf(nv[j], frcp(fmaf(e1[j], ee[j], 1.0f)), acc1);
        acc2 = fmaf(nv[j], frcp(fmaf(e2[j], ee[j], 1.0f)), acc2);
        acc3 = fmaf(nv[j], frcp(fmaf(e3[j], ee[j], 1.0f)), acc3);
      }
    }
    __syncthreads();
  }

  // ---- phase 2: softmax over t per s-row ----
  Mu[0][t] = acc0;
  Mu[1][t] = acc1;
  Mu[2][t] = acc2;
  Mu[3][t] = acc3;
  __syncthreads();
  {
    float4 v = *(const float4*)&Mu[w][lane * 4];
    float m = fmaxf(fmaxf(v.x, v.y), fmaxf(v.z, v.w));
#pragma unroll
    for (int off = 32; off > 0; off >>= 1) m = fmaxf(m, __shfl_xor(m, off));
    float4 e;
    e.x = fexp2((v.x - m) * LOG2E_F);
    e.y = fexp2((v.y - m) * LOG2E_F);
    e.z = fexp2((v.z - m) * LOG2E_F);
    e.w = fexp2((v.w - m) * LOG2E_F);
    float sm = (e.x + e.y) + (e.z + e.w);
#pragma unroll
    for (int off = 32; off > 0; off >>= 1) sm += __shfl_xor(sm, off);
    const float inv = frcp(sm);
    e.x *= inv; e.y *= inv; e.z *= inv; e.w *= inv;
    *(float4*)&Mu[w][lane * 4] = e;
    if (lane == 0) maxmu[b * TD_ + sBase + w] = m;
  }
  __syncthreads();

  // ---- phase 3: sum_en = alphas @ en ----
  // wave w owns t's {t0 + w*4 .. t0 + w*4+3} each chunk; lane owns d-quad.
  float4 p0 = {0, 0, 0, 0}, p1 = {0, 0, 0, 0}, p2 = {0, 0, 0, 0}, p3 = {0, 0, 0, 0};
  for (int t0 = 0; t0 < TE_; t0 += 16) {
    // stage EN[tl][d] into EeT space (16 rows x 256 d), coalesced b128
#pragma unroll
    for (int k = 0; k < 4; ++k) {
      const int f = tid + 256 * k;
      const int r = f >> 6, c4 = f & 63;
      *(float4*)&EeT[r][c4 * 4] =
          *(const float4*)&en[(b * TE_ + t0 + r) * D_ + c4 * 4];
    }
    __syncthreads();
    float a0[4], a1[4], a2[4], a3[4];
    *(float4*)a0 = *(const float4*)&Mu[0][t0 + w * 4];  // broadcast
    *(float4*)a1 = *(const float4*)&Mu[1][t0 + w * 4];
    *(float4*)a2 = *(const float4*)&Mu[2][t0 + w * 4];
    *(float4*)a3 = *(const float4*)&Mu[3][t0 + w * 4];
#pragma unroll
    for (int j = 0; j < 4; ++j) {
      const float4 env = *(const float4*)&EeT[w * 4 + j][lane * 4];
      p0.x = fmaf(a0[j], env.x, p0.x); p0.y = fmaf(a0[j], env.y, p0.y);
      p0.z = fmaf(a0[j], env.z, p0.z); p0.w = fmaf(a0[j], env.w, p0.w);
      p1.x = fmaf(a1[j], env.x, p1.x); p1.y = fmaf(a1[j], env.y, p1.y);
      p1.z = fmaf(a1[j], env.z, p1.z); p1.w = fmaf(a1[j], env.w, p1.w);
      p2.x = fmaf(a2[j], env.x, p2.x); p2.y = fmaf(a2[j], env.y, p2.y);
      p2.z = fmaf(a2[j], env.z, p2.z); p2.w = fmaf(a2[j], env.w, p2.w);
      p3.x = fmaf(a3[j], env.x, p3.x); p3.y = fmaf(a3[j], env.y, p3.y);
      p3.z = fmaf(a3[j], env.z, p3.z); p3.w = fmaf(a3[j], env.w, p3.w);
    }
    __syncthreads();
  }
  // cross-wave reduce via EeT space: slot ((w*4+s)*64 + lane) float4s
  {
    float* RED = &EeT[0][0];  // 4160 floats >= 4096
    *(float4*)&RED[((w * 4 + 0) * 64 + lane) * 4] = p0;
    *(float4*)&RED[((w * 4 + 1) * 64 + lane) * 4] = p1;
    *(float4*)&RED[((w * 4 + 2) * 64 + lane) * 4] = p2;
    *(float4*)&RED[((w * 4 + 3) * 64 + lane) * 4] = p3;
    __syncthreads();
    const int s = tid >> 6, l = tid & 63;  // wave handles one s-row output
    float4 sum = {0, 0, 0, 0};
#pragma unroll
    for (int ww = 0; ww < 4; ++ww) {
      const float4 q = *(const float4*)&RED[((ww * 4 + s) * 64 + l) * 4];
      sum.x += q.x; sum.y += q.y; sum.z += q.z; sum.w += q.w;
    }
    *(float4*)&sum_en[(b * TD_ + sBase + s) * D_ + l * 4] = sum;
  }
}

// ---------------------------------------------------------------------------
// KC: per block (b, 8 s-rows): recompute max_alphas softmax (256 vals, cheap),
// h_hat[d] = sum_s de[b,s,d]*malpha[s] (coalesced, L2-hot de), then fused
// concat: out = [de | sum_en | de*sum_en | de*h_hat]. grid (32, 8).
// ---------------------------------------------------------------------------
__global__ __launch_bounds__(256) void coatt_kc_out(
    const float* __restrict__ de, const float* __restrict__ ws,
    float* __restrict__ out) {
  const float* __restrict__ sum_en = ws + SUMEN_OFF;
  const float* __restrict__ maxmu = ws + MAXMU_OFF;
  const int b = blockIdx.y;
  const int sBase = blockIdx.x * 8;
  const int tid = threadIdx.x;
  const int w = tid >> 6, lane = tid & 63;
  __shared__ float malpha[256];
  __shared__ float red[8];
  __shared__ float hhL[256];
  // softmax over s of maxmu[b,:]
  const float v = maxmu[b * TD_ + tid];
  float m = v;
#pragma unroll
  for (int off = 32; off > 0; off >>= 1) m = fmaxf(m, __shfl_xor(m, off));
  if (lane == 0) red[w] = m;
  __syncthreads();
  m = fmaxf(fmaxf(red[0], red[1]), fmaxf(red[2], red[3]));
  const float e = fexp2((v - m) * LOG2E_F);
  float sm = e;
#pragma unroll
  for (int off = 32; off > 0; off >>= 1) sm += __shfl_xor(sm, off);
  if (lane == 0) red[4 + w] = sm;
  __syncthreads();
  sm = (red[4] + red[5]) + (red[6] + red[7]);
  malpha[tid] = e * frcp(sm);
  __syncthreads();
  // h_hat for d = tid (coalesced loads, broadcast malpha)
  float hh = 0.f;
#pragma unroll 8
  for (int s = 0; s < TD_; ++s)
    hh = fmaf(de[(b * TD_ + s) * D_ + tid], malpha[s], hh);
  hhL[tid] = hh;
  __syncthreads();
  // concat output: 4 rows per pass, 2 passes
#pragma unroll
  for (int pass = 0; pass < 2; ++pass) {
    const int s = sBase + pass * 4 + w;
    const float4 d4 = *(const float4*)&de[(b * TD_ + s) * D_ + lane * 4];
    const float4 se4 = *(const float4*)&sum_en[(b * TD_ + s) * D_ + lane * 4];
    const float4 hh4 = *(const float4*)&hhL[lane * 4];
    float* o = out + (size_t)(b * TD_ + s) * (4 * D_);
    *(float4*)&o[lane * 4] = d4;
    *(float4*)&o[D_ + lane * 4] = se4;
    float4 pr;
    pr.x = d4.x * se4.x; pr.y = d4.y * se4.y;
    pr.z = d4.z * se4.z; pr.w = d4.w * se4.w;
    *(float4*)&o[2 * D_ + lane * 4] = pr;
    float4 q;
    q.x = d4.x * hh4.x; q.y = d4.y * hh4.y;
    q.z = d4.z * hh4.z; q.w = d4.w * hh4.w;
    *(float4*)&o[3 * D_ + lane * 4] = q;
  }
}

extern "C" void kernel_launch(void* const* d_in, const int* in_sizes, int n_in,
                              void* d_out, int out_size, void* d_ws, size_t ws_size,
                              hipStream_t stream) {
  (void)in_sizes; (void)n_in; (void)out_size; (void)ws_size;
  const float* en   = (const float*)d_in[0];
  const float* de   = (const float*)d_in[1];
  const float* w_en = (const float*)d_in[2];
  const float* w_de = (const float*)d_in[3];
  const float* nu   = (const float*)d_in[4];
  float* out = (float*)d_out;
  float* ws  = (float*)d_ws;

  coatt_ka_proj<<<dim3(4, 32, 2), 256, 0, stream>>>(en, de, w_en, w_de, ws);
  coatt_kb_fused<<<dim3(64, 8), 256, 0, stream>>>(nu, en, ws);
  coatt_kc_out<<<dim3(32, 8), 256, 0, stream>>>(de, ws, out);
}

// Round 4
// 121.896 us; speedup vs baseline: 1.0862x; 1.0862x over previous
//
#include <hip/hip_runtime.h>

// Problem constants
#define B_   8
#define TE_  256
#define TD_  256
#define D_   256
#define U_   256

// Workspace layout (float offsets). ~6 MB.
#define EET_OFF   0        // (B, U, TE)  Ee^T = exp2(2log2e * en@w_en), TRANSPOSED
#define ED_OFF    524288   // (B, TD, U)  Ed = exp2(2log2e * de@w_de)
#define ALPHA_OFF 1048576  // (B, TD, TE) alphas
#define MAXMU_OFF 1572864  // (B, TD)     row max of mu'
#define HH_OFF    1574912  // (B, D)      h_hat

__device__ __forceinline__ float fexp2(float x) {
#if __has_builtin(__builtin_amdgcn_exp2f)
  return __builtin_amdgcn_exp2f(x);
#else
  return exp2f(x);
#endif
}
__device__ __forceinline__ float frcp(float x) {
#if __has_builtin(__builtin_amdgcn_rcpf)
  return __builtin_amdgcn_rcpf(x);
#else
  return 1.0f / x;
#endif
}

#define LOG2E_F 1.4426950408889634f
#define TWO_LOG2E_F 2.8853900817779268f

// ---------------------------------------------------------------------------
// K1: Ed = exp2(2log2e * de@w_de) row-major; Ee^T = exp2(2log2e * en@w_en)
// written TRANSPOSED [b][u][t] via LDS transpose epilogue (so K2's Ee access
// is a coalesced global load with t=tid — no LDS in the hot kernel).
// 64x64 tile, 4x4 microtile, K-chunks of 32, DOUBLE-BUFFERED (1 barrier/iter).
// grid (4, 32, 2) = 256 blocks.
// ---------------------------------------------------------------------------
__global__ __launch_bounds__(256) void coatt_k1_proj(
    const float* __restrict__ en, const float* __restrict__ de,
    const float* __restrict__ w_en, const float* __restrict__ w_de,
    float* __restrict__ ws) {
  const int which = blockIdx.z;  // 0: en->EeT (transposed), 1: de->Ed (direct)
  const float* __restrict__ A = which ? de : en;     // (2048, 256)
  const float* __restrict__ W = which ? w_de : w_en; // (256, 256)
  const int rowBase = blockIdx.y * 64;   // global row in (B*T)
  const int colBase = blockIdx.x * 64;   // col in U
  __shared__ float As[2][32][68];  // [buf][k][row]
  __shared__ float Bs[2][32][68];  // [buf][k][col]
  const int tid = threadIdx.x;
  const int tx = tid & 15, ty = tid >> 4;

  // staging index helpers (chunk = 32 k)
  const int aRow0 = tid >> 3, aC4 = tid & 7;          // +256: row+32
  const int bK0 = tid >> 4, bC4 = tid & 15;           // +256: k+16
  float4 aR[2], bR[2];

  // prologue: load + write chunk 0
#pragma unroll
  for (int kk = 0; kk < 2; ++kk) {
    aR[kk] = *(const float4*)&A[(rowBase + aRow0 + 32 * kk) * D_ + aC4 * 4];
    bR[kk] = *(const float4*)&W[(bK0 + 16 * kk) * U_ + colBase + bC4 * 4];
  }
#pragma unroll
  for (int kk = 0; kk < 2; ++kk) {
    float v[4]; *(float4*)v = aR[kk];
#pragma unroll
    for (int j = 0; j < 4; ++j) As[0][aC4 * 4 + j][aRow0 + 32 * kk] = v[j];
    *(float4*)&Bs[0][bK0 + 16 * kk][bC4 * 4] = bR[kk];
  }
  __syncthreads();

  float acc[4][4] = {};
#define K1_COMPUTE(BUF)                                            \
  _Pragma("unroll")                                                \
  for (int k = 0; k < 32; ++k) {                                   \
    float av[4], bv[4];                                            \
    *(float4*)av = *(const float4*)&As[BUF][k][ty * 4];            \
    *(float4*)bv = *(const float4*)&Bs[BUF][k][tx * 4];            \
    _Pragma("unroll")                                              \
    for (int i = 0; i < 4; ++i)                                    \
      _Pragma("unroll")                                            \
      for (int j = 0; j < 4; ++j)                                  \
        acc[i][j] = fmaf(av[i], bv[j], acc[i][j]);                 \
  }

  for (int kc = 0; kc < 7; ++kc) {
    const int k0 = (kc + 1) * 32;
#pragma unroll
    for (int kk = 0; kk < 2; ++kk) {
      aR[kk] = *(const float4*)&A[(rowBase + aRow0 + 32 * kk) * D_ + k0 + aC4 * 4];
      bR[kk] = *(const float4*)&W[(k0 + bK0 + 16 * kk) * U_ + colBase + bC4 * 4];
    }
    const int cur = kc & 1, nxt = cur ^ 1;
    K1_COMPUTE(cur)
#pragma unroll
    for (int kk = 0; kk < 2; ++kk) {
      float v[4]; *(float4*)v = aR[kk];
#pragma unroll
      for (int j = 0; j < 4; ++j) As[nxt][aC4 * 4 + j][aRow0 + 32 * kk] = v[j];
      *(float4*)&Bs[nxt][bK0 + 16 * kk][bC4 * 4] = bR[kk];
    }
    __syncthreads();
  }
  K1_COMPUTE(1)
  __syncthreads();  // As dead after this; reused as Cs for transpose

  if (which) {
    // Ed: direct row-major store
    float* __restrict__ out = ws + ED_OFF;
#pragma unroll
    for (int i = 0; i < 4; ++i) {
      float4 o;
      o.x = fexp2(acc[i][0] * TWO_LOG2E_F);
      o.y = fexp2(acc[i][1] * TWO_LOG2E_F);
      o.z = fexp2(acc[i][2] * TWO_LOG2E_F);
      o.w = fexp2(acc[i][3] * TWO_LOG2E_F);
      *(float4*)&out[(rowBase + ty * 4 + i) * U_ + colBase + tx * 4] = o;
    }
  } else {
    // EeT: transpose via LDS (Cs[ucol][row], 64x68, reuses As memory)
    float* Cs = &As[0][0][0];  // 2*32*68 = 4352 floats = 64*68 exactly
#pragma unroll
    for (int i = 0; i < 4; ++i)
#pragma unroll
      for (int j = 0; j < 4; ++j)
        Cs[(tx * 4 + j) * 68 + ty * 4 + i] = fexp2(acc[i][j] * TWO_LOG2E_F);
    __syncthreads();
    float* __restrict__ out = ws + EET_OFF;
    const int b = rowBase >> 8, t0 = rowBase & 255;
#pragma unroll
    for (int kk = 0; kk < 4; ++kk) {
      const int q = tid + 256 * kk;
      const int uc = q >> 4, tq = q & 15;
      const float4 v = *(const float4*)&Cs[uc * 68 + tq * 4];
      *(float4*)&out[(size_t)(b * U_ + colBase + uc) * TE_ + t0 + tq * 4] = v;
    }
  }
}

// ---------------------------------------------------------------------------
// K2 (dominant, trans-pipe-bound): per block (b, 4 s-rows), thread t = tid.
//   mu'[s][t] = -2 * sum_u nu_u * rcp(fma(Ed[s,u], EeT[u,t], 1))
// EeT read: coalesced global dword (lane=t). Ed/nu: wave-uniform -> s_load
// (SGPR operands, off LDS & vector-VMEM pipes). ZERO LDS in the u-loop.
// Fused row-softmax over t (shuffle + 16-float LDS cross-wave patch).
// grid (64, 8) = 512 blocks.
// ---------------------------------------------------------------------------
__global__ __launch_bounds__(256) void coatt_k2_mu(
    const float* __restrict__ nu, float* __restrict__ ws) {
  const float* __restrict__ EeT = ws + EET_OFF;
  const float* __restrict__ Ed = ws + ED_OFF;
  float* __restrict__ alphas = ws + ALPHA_OFF;
  float* __restrict__ maxmu = ws + MAXMU_OFF;
  const int b = blockIdx.y;
  const int sBase = blockIdx.x * 4;
  const int tid = threadIdx.x;
  const int w = tid >> 6, lane = tid & 63;
  const float* __restrict__ Ee_b = EeT + (size_t)b * U_ * TE_ + tid;  // lane-coalesced
  const float* __restrict__ Ed_b = Ed + (size_t)(b * TD_ + sBase) * U_;  // uniform

  float acc0 = 0.f, acc1 = 0.f, acc2 = 0.f, acc3 = 0.f;
#pragma unroll 4
  for (int u4 = 0; u4 < 64; ++u4) {
    const float4 nv = *(const float4*)&nu[u4 * 4];          // uniform -> SGPR
    const float4 e0 = *(const float4*)&Ed_b[0 * U_ + u4 * 4];
    const float4 e1 = *(const float4*)&Ed_b[1 * U_ + u4 * 4];
    const float4 e2 = *(const float4*)&Ed_b[2 * U_ + u4 * 4];
    const float4 e3 = *(const float4*)&Ed_b[3 * U_ + u4 * 4];
    float ee[4];
#pragma unroll
    for (int j = 0; j < 4; ++j) ee[j] = Ee_b[(u4 * 4 + j) * TE_];  // coalesced
    const float* nvp = (const float*)&nv;
    const float* p0 = (const float*)&e0;
    const float* p1 = (const float*)&e1;
    const float* p2 = (const float*)&e2;
    const float* p3 = (const float*)&e3;
#pragma unroll
    for (int j = 0; j < 4; ++j) {
      acc0 = fmaf(nvp[j], frcp(fmaf(p0[j], ee[j], 1.0f)), acc0);
      acc1 = fmaf(nvp[j], frcp(fmaf(p1[j], ee[j], 1.0f)), acc1);
      acc2 = fmaf(nvp[j], frcp(fmaf(p2[j], ee[j], 1.0f)), acc2);
      acc3 = fmaf(nvp[j], frcp(fmaf(p3[j], ee[j], 1.0f)), acc3);
    }
  }
  // mu' = -2*acc. Fused softmax over t (256 threads = 4 waves).
  float v[4] = {-2.f * acc0, -2.f * acc1, -2.f * acc2, -2.f * acc3};
  __shared__ float part[4][4];  // [s][wave]
  float m[4];
#pragma unroll
  for (int s = 0; s < 4; ++s) {
    m[s] = v[s];
#pragma unroll
    for (int off = 32; off > 0; off >>= 1) m[s] = fmaxf(m[s], __shfl_xor(m[s], off));
    if (lane == 0) part[s][w] = m[s];
  }
  __syncthreads();
#pragma unroll
  for (int s = 0; s < 4; ++s)
    m[s] = fmaxf(fmaxf(part[s][0], part[s][1]), fmaxf(part[s][2], part[s][3]));
  __syncthreads();
  float e[4], sm[4];
#pragma unroll
  for (int s = 0; s < 4; ++s) {
    e[s] = fexp2((v[s] - m[s]) * LOG2E_F);
    sm[s] = e[s];
#pragma unroll
    for (int off = 32; off > 0; off >>= 1) sm[s] += __shfl_xor(sm[s], off);
    if (lane == 0) part[s][w] = sm[s];
  }
  __syncthreads();
  float* __restrict__ al = alphas + (size_t)(b * TD_ + sBase) * TE_;
#pragma unroll
  for (int s = 0; s < 4; ++s) {
    const float tot = (part[s][0] + part[s][1]) + (part[s][2] + part[s][3]);
    al[s * TE_ + tid] = e[s] * frcp(tot);
  }
  if (tid == 0) {
#pragma unroll
    for (int s = 0; s < 4; ++s) maxmu[b * TD_ + sBase + s] = m[s];
  }
}

// ---------------------------------------------------------------------------
// K3: max_alphas = softmax_s(maxmu[b,:]); h_hat[b,d] = sum_s de[b,s,d]*ma[s].
// grid (8 dChunks, 8 b), 256 threads.
// ---------------------------------------------------------------------------
__global__ __launch_bounds__(256) void coatt_k3_hhat(
    const float* __restrict__ de, float* __restrict__ ws) {
  const float* __restrict__ maxmu = ws + MAXMU_OFF;
  float* __restrict__ hhat = ws + HH_OFF;
  const int b = blockIdx.y;
  const int dBase = blockIdx.x * 32;
  const int tid = threadIdx.x;
  const int w = tid >> 6, lane = tid & 63;
  __shared__ float red[8];
  __shared__ float malpha[256];
  __shared__ float acc_red[256];
  const float v = maxmu[b * TD_ + tid];
  float m = v;
#pragma unroll
  for (int off = 32; off > 0; off >>= 1) m = fmaxf(m, __shfl_xor(m, off));
  if (lane == 0) red[w] = m;
  __syncthreads();
  m = fmaxf(fmaxf(red[0], red[1]), fmaxf(red[2], red[3]));
  const float e = fexp2((v - m) * LOG2E_F);
  float sm = e;
#pragma unroll
  for (int off = 32; off > 0; off >>= 1) sm += __shfl_xor(sm, off);
  if (lane == 0) red[4 + w] = sm;
  __syncthreads();
  sm = (red[4] + red[5]) + (red[6] + red[7]);
  malpha[tid] = e * frcp(sm);
  __syncthreads();
  const int dl = tid & 31, sg = tid >> 5;
  float acc = 0.f;
  for (int s = sg * 32; s < sg * 32 + 32; ++s)
    acc = fmaf(de[(b * TD_ + s) * D_ + dBase + dl], malpha[s], acc);
  acc_red[tid] = acc;
  __syncthreads();
  if (tid < 32) {
    float t = acc_red[tid];
#pragma unroll
    for (int g = 1; g < 8; ++g) t += acc_red[g * 32 + tid];
    hhat[b * D_ + dBase + tid] = t;
  }
}

// ---------------------------------------------------------------------------
// K4: sum_en[s,d] = sum_t alphas[s,t]*en[t,d] with alphas via SCALAR loads
// (uniform per block) and en coalesced (lane=d). Fused concat epilogue:
// out = [de | sum_en | de*sum_en | de*h_hat]. grid (64, 8) = 512 blocks.
// ---------------------------------------------------------------------------
__global__ __launch_bounds__(256) void coatt_k4_out(
    const float* __restrict__ en, const float* __restrict__ de,
    const float* __restrict__ ws, float* __restrict__ out) {
  const float* __restrict__ alphas = ws + ALPHA_OFF;
  const float* __restrict__ hhat = ws + HH_OFF;
  const int b = blockIdx.y;
  const int sBase = blockIdx.x * 4;
  const int d = threadIdx.x;
  const float* __restrict__ al = alphas + (size_t)(b * TD_ + sBase) * TE_;  // uniform
  const float* __restrict__ en_b = en + (size_t)b * TE_ * D_ + d;           // coalesced

  float acc0 = 0.f, acc1 = 0.f, acc2 = 0.f, acc3 = 0.f;
#pragma unroll 4
  for (int t4 = 0; t4 < 64; ++t4) {
    const float4 a0 = *(const float4*)&al[0 * TE_ + t4 * 4];  // uniform -> SGPR
    const float4 a1 = *(const float4*)&al[1 * TE_ + t4 * 4];
    const float4 a2 = *(const float4*)&al[2 * TE_ + t4 * 4];
    const float4 a3 = *(const float4*)&al[3 * TE_ + t4 * 4];
    float env[4];
#pragma unroll
    for (int j = 0; j < 4; ++j) env[j] = en_b[(t4 * 4 + j) * D_];  // coalesced
    const float* q0 = (const float*)&a0;
    const float* q1 = (const float*)&a1;
    const float* q2 = (const float*)&a2;
    const float* q3 = (const float*)&a3;
#pragma unroll
    for (int j = 0; j < 4; ++j) {
      acc0 = fmaf(q0[j], env[j], acc0);
      acc1 = fmaf(q1[j], env[j], acc1);
      acc2 = fmaf(q2[j], env[j], acc2);
      acc3 = fmaf(q3[j], env[j], acc3);
    }
  }
  const float hh = hhat[b * D_ + d];
  const float se[4] = {acc0, acc1, acc2, acc3};
#pragma unroll
  for (int s = 0; s < 4; ++s) {
    const float dd = de[(size_t)(b * TD_ + sBase + s) * D_ + d];
    float* o = out + (size_t)(b * TD_ + sBase + s) * (4 * D_);
    o[d] = dd;
    o[D_ + d] = se[s];
    o[2 * D_ + d] = dd * se[s];
    o[3 * D_ + d] = dd * hh;
  }
}

extern "C" void kernel_launch(void* const* d_in, const int* in_sizes, int n_in,
                              void* d_out, int out_size, void* d_ws, size_t ws_size,
                              hipStream_t stream) {
  (void)in_sizes; (void)n_in; (void)out_size; (void)ws_size;
  const float* en   = (const float*)d_in[0];
  const float* de   = (const float*)d_in[1];
  const float* w_en = (const float*)d_in[2];
  const float* w_de = (const float*)d_in[3];
  const float* nu   = (const float*)d_in[4];
  float* out = (float*)d_out;
  float* ws  = (float*)d_ws;

  coatt_k1_proj<<<dim3(4, 32, 2), 256, 0, stream>>>(en, de, w_en, w_de, ws);
  coatt_k2_mu<<<dim3(64, 8), 256, 0, stream>>>(nu, ws);
  coatt_k3_hhat<<<dim3(8, 8), 256, 0, stream>>>(de, ws);
  coatt_k4_out<<<dim3(64, 8), 256, 0, stream>>>(en, de, ws, out);
}